// Round 3
// baseline (503.994 us; speedup 1.0000x reference)
//
#include <hip/hip_runtime.h>
#include <hip/hip_fp16.h>
#include <math.h>
#include <stdint.h>

#define D_DIM    512
#define NCLS     1000
#define KSEL     200
#define NBINS    1024         // bin width 2.0, covers d2 in [0, 2048)
#define HREP     4            // replicated LDS histograms (atomic contention)
#define CAND_MAX 2048
#define GCONST   0.005        // 1/(2*sigma^2), sigma=10
#define MARGIN   4.0f         // covers f16-d2 ulp (0.5) + bf16 GEMM error + bin edge

typedef short s8v __attribute__((ext_vector_type(8)));
typedef float f4v __attribute__((ext_vector_type(4)));

#define GLOAD_LDS16(gp, lp) __builtin_amdgcn_global_load_lds( \
    (const __attribute__((address_space(1))) void*)(gp),      \
    (__attribute__((address_space(3))) void*)(lp), 16, 0, 0)

// RTNE f32 -> bf16 (inputs finite)
static __device__ __forceinline__ unsigned short f2bf(float x) {
    unsigned u = __float_as_uint(x);
    return (unsigned short)((u + 0x7FFFu + ((u >> 16) & 1u)) >> 16);
}

// packed RTNE f32x2 -> bf16x2, single instruction (no builtin on gfx950)
static __device__ __forceinline__ unsigned cvt_pk_bf16(float lo, float hi) {
    unsigned r;
    asm("v_cvt_pk_bf16_f32 %0, %1, %2" : "=v"(r) : "v"(lo), "v"(hi));
    return r;
}

// ------------------------------------------------- convert F (+ row norms)
__global__ __launch_bounds__(256)
void convertF(const float* __restrict__ F, unsigned short* __restrict__ Fb,
              float* __restrict__ f2)
{
    __shared__ float red[256];
    const int r = blockIdx.x, t = threadIdx.x;
    float2 v = *(const float2*)(F + (size_t)r * D_DIM + t * 2);
    ushort2 o; o.x = f2bf(v.x); o.y = f2bf(v.y);
    *(ushort2*)(Fb + (size_t)r * D_DIM + t * 2) = o;
    red[t] = v.x * v.x + v.y * v.y;
    __syncthreads();
    for (int off = 128; off > 0; off >>= 1) {
        if (t < off) red[t] += red[t + off];
        __syncthreads();
    }
    if (t == 0) f2[r] = red[0];
}

// ------------------------------------------------- convert C (+ row norms)
// One wave per row (D=512 f32 = 64 lanes x 8 floats), grid-stride.
__global__ __launch_bounds__(256)
void convertC(const float* __restrict__ C, unsigned short* __restrict__ Cb,
              float* __restrict__ c2, int N)
{
    const int wv = threadIdx.x >> 6, lane = threadIdx.x & 63;
    const int stride = gridDim.x * 4;
    for (int r = blockIdx.x * 4 + wv; r < N; r += stride) {
        const float* rp = C + (size_t)r * D_DIM + lane * 8;
        float4 a = *(const float4*)rp;
        float4 b = *(const float4*)(rp + 4);
        uint4 o;
        o.x = cvt_pk_bf16(a.x, a.y);
        o.y = cvt_pk_bf16(a.z, a.w);
        o.z = cvt_pk_bf16(b.x, b.y);
        o.w = cvt_pk_bf16(b.z, b.w);
        *(uint4*)(Cb + (size_t)r * D_DIM + lane * 8) = o;
        float s = a.x*a.x + a.y*a.y + a.z*a.z + a.w*a.w
                + b.x*b.x + b.y*b.y + b.z*b.z + b.w*b.w;
        s += __shfl_xor(s, 1, 64);
        s += __shfl_xor(s, 2, 64);
        s += __shfl_xor(s, 4, 64);
        s += __shfl_xor(s, 8, 64);
        s += __shfl_xor(s, 16, 64);
        s += __shfl_xor(s, 32, 64);
        if (lane == 0) c2[r] = s;
    }
}

// ------------------------------------------------- PURE MFMA GEMM, BM=256
// 512 threads = 8 waves (4m x 2n), per-wave 64x64 output (4x4 16x16 frags).
// Both A and B staged via global_load_lds w=16 from bf16, octet-XOR swizzle
// on the per-lane GLOBAL source address (LDS dest linear). Epilogue computes
// d2 = f2[m] + c2[n] - 2*S directly and stores f16 d2 (select needs no c2).
__global__ __launch_bounds__(512)
void mfma_gemm_pure(const unsigned short* __restrict__ Fb,
                    const unsigned short* __restrict__ Cb,
                    const float* __restrict__ f2,
                    const float* __restrict__ c2,
                    __half* __restrict__ Dm, int N)
{
    __shared__ short smem[32 * 512 + 16 * 512];  // As 32 KB | Bs 16 KB
    short* As = smem;
    short* Bs = smem + 32 * 512;
    const int t    = threadIdx.x;
    const int lane = t & 63;
    const int w    = t >> 6;             // wave 0..7
    const int wm   = w >> 1, wn = w & 1; // wm 0..3 (64 rows each), wn 0..1 (64 cols)
    const int m0   = blockIdx.x * 256;   // m fastest
    const int n0   = blockIdx.y * 128;
    const int lrow = lane >> 3;          // 0..7 within staging chunk
    const int oct  = (lane & 7) ^ lrow;  // swizzled global k octet
    const int quad = lane >> 4;          // 0..3
    const int col  = lane & 15;

    f4v acc[4][4];
#pragma unroll
    for (int i = 0; i < 4; ++i)
#pragma unroll
        for (int j = 0; j < 4; ++j) acc[i][j] = (f4v){0.f, 0.f, 0.f, 0.f};

    for (int k0 = 0; k0 < D_DIM; k0 += 64) {
        __syncthreads();             // prev iter's MFMA done with LDS
#pragma unroll
        for (int cc = 0; cc < 4; ++cc) {
            int ch = w * 4 + cc;     // A chunks 0..31 (8 rows each, 256 rows)
            GLOAD_LDS16(Fb + (size_t)(m0 + ch * 8 + lrow) * D_DIM + k0 + oct * 8,
                        &As[ch * 512]);
        }
#pragma unroll
        for (int cc = 0; cc < 2; ++cc) {
            int ch = w * 2 + cc;     // B chunks 0..15 (128 rows)
            int rg = n0 + ch * 8 + lrow;
            rg = rg < N ? rg : N - 1;   // clamp tail
            GLOAD_LDS16(Cb + (size_t)rg * D_DIM + k0 + oct * 8,
                        &Bs[ch * 512]);
        }
        __syncthreads();             // barrier drains vmcnt: tiles ready

#pragma unroll
        for (int kk = 0; kk < 2; ++kk) {
            int slot = (kk * 4 + quad) ^ (col & 7);
            s8v b[4];
#pragma unroll
            for (int j = 0; j < 4; ++j) {
                int row = wn * 64 + j * 16 + col;
                b[j] = *(s8v*)&Bs[row * 64 + slot * 8];
            }
#pragma unroll
            for (int i = 0; i < 4; ++i) {
                int row = wm * 64 + i * 16 + col;
                s8v a = *(s8v*)&As[row * 64 + slot * 8];
#pragma unroll
                for (int j = 0; j < 4; ++j)
                    acc[i][j] = __builtin_amdgcn_mfma_f32_16x16x32_bf16(
                        a, b[j], acc[i][j], 0, 0, 0);
            }
        }
    }

    // ---- epilogue: d2 = f2[m] + c2[n] - 2*S, pack f16 (octet-swizzled), store
    float c2v[4];
#pragma unroll
    for (int j = 0; j < 4; ++j) {
        int idx = n0 + wn * 64 + j * 16 + col;
        idx = idx < N ? idx : N - 1;
        c2v[j] = c2[idx];
    }
    float fv[4][4];
#pragma unroll
    for (int i = 0; i < 4; ++i)
#pragma unroll
        for (int v = 0; v < 4; ++v)
            fv[i][v] = f2[m0 + wm * 64 + i * 16 + quad * 4 + v];

    __half* Cs = (__half*)smem;      // 128 x 128 f16 = 32 KB (half tile)
#pragma unroll
    for (int h = 0; h < 2; ++h) {
        __syncthreads();             // MFMA done (h=0) / prev half stored (h=1)
        if ((wm >> 1) == h) {
            int mlb = (wm & 1) * 64;
#pragma unroll
            for (int i = 0; i < 4; ++i) {
#pragma unroll
                for (int j = 0; j < 4; ++j) {
#pragma unroll
                    for (int v = 0; v < 4; ++v) {
                        int ml = mlb + i * 16 + quad * 4 + v;   // 0..127
                        int nl = wn * 64 + j * 16 + col;        // 0..127
                        float d2 = fv[i][v] + c2v[j] - 2.f * acc[i][j][v];
                        int slot = (nl >> 3) ^ (ml & 7);
                        Cs[ml * 128 + slot * 8 + (nl & 7)] = __float2half(d2);
                    }
                }
            }
        }
        __syncthreads();
#pragma unroll
        for (int it = 0; it < 4; ++it) {
            int idx = it * 512 + t;  // 0..2047
            int row = idx >> 4;      // 0..127
            int o8  = idx & 15;
            int n   = n0 + o8 * 8;
            const __half* src = &Cs[row * 128 + ((o8 ^ (row & 7)) * 8)];
            __half* dst = Dm + (size_t)(m0 + h * 128 + row) * N + n;
            if (n + 7 < N) {
                *(uint4*)dst = *(const uint4*)src;
            } else if (n < N) {
                for (int e = 0; e < 8 && n + e < N; ++e) dst[e] = src[e];
            }
        }
    }
}

// ------------------------------------------------- FUSED MFMA GEMM (f32 C in)
// Fallback when workspace can't hold Cb. Writes S (not d2); select mode 0.
__global__ __launch_bounds__(256)
void mfma_gemm_fused(const unsigned short* __restrict__ Fb,
                     const float* __restrict__ C,
                     float* __restrict__ c2g,
                     __half* __restrict__ Sm, int N)
{
    __shared__ short smem[2 * 128 * 64];
    short* As = smem;
    short* Bs = smem + 128 * 64;
    const int t    = threadIdx.x;
    const int lane = t & 63;
    const int w    = t >> 6;
    const int wm   = w >> 1, wn = w & 1;
    const int m0   = blockIdx.x * 128;
    const int n0   = blockIdx.y * 128;
    const int lrow = lane >> 3;
    const int oct  = (lane & 7) ^ lrow;
    const int quad = lane >> 4;
    const int col  = lane & 15;

    f4v acc[4][4];
#pragma unroll
    for (int i = 0; i < 4; ++i)
#pragma unroll
        for (int j = 0; j < 4; ++j) acc[i][j] = (f4v){0.f, 0.f, 0.f, 0.f};

    float  c2part[4] = {0.f, 0.f, 0.f, 0.f};
    float4 ra[4], rb[4];

#pragma unroll
    for (int cc = 0; cc < 4; ++cc) {
        int row = (w * 4 + cc) * 8 + lrow;
        int rg  = n0 + row; rg = rg < N ? rg : N - 1;
        const float* gp = C + (size_t)rg * D_DIM + oct * 8;
        ra[cc] = *(const float4*)gp;
        rb[cc] = *(const float4*)(gp + 4);
    }

    for (int k0 = 0; k0 < D_DIM; k0 += 64) {
        __syncthreads();
#pragma unroll
        for (int cc = 0; cc < 4; ++cc) {
            int ch = w * 4 + cc;
            GLOAD_LDS16(Fb + (size_t)(m0 + ch * 8 + lrow) * D_DIM + k0 + oct * 8,
                        &As[ch * 512]);
        }
#pragma unroll
        for (int cc = 0; cc < 4; ++cc) {
            int row = (w * 4 + cc) * 8 + lrow;
            float4 va = ra[cc], vb = rb[cc];
            c2part[cc] += va.x*va.x + va.y*va.y + va.z*va.z + va.w*va.w
                        + vb.x*vb.x + vb.y*vb.y + vb.z*vb.z + vb.w*vb.w;
            uint4 o;
            o.x = cvt_pk_bf16(va.x, va.y);
            o.y = cvt_pk_bf16(va.z, va.w);
            o.z = cvt_pk_bf16(vb.x, vb.y);
            o.w = cvt_pk_bf16(vb.z, vb.w);
            *(uint4*)&Bs[row * 64 + (lane & 7) * 8] = o;
        }
        __syncthreads();

        if (k0 + 64 < D_DIM) {
#pragma unroll
            for (int cc = 0; cc < 4; ++cc) {
                int row = (w * 4 + cc) * 8 + lrow;
                int rg  = n0 + row; rg = rg < N ? rg : N - 1;
                const float* gp = C + (size_t)rg * D_DIM + (k0 + 64) + oct * 8;
                ra[cc] = *(const float4*)gp;
                rb[cc] = *(const float4*)(gp + 4);
            }
        }

#pragma unroll
        for (int kk = 0; kk < 2; ++kk) {
            s8v a[4], b[4];
#pragma unroll
            for (int i = 0; i < 4; ++i) {
                int row  = wm * 64 + i * 16 + col;
                int slot = (kk * 4 + quad) ^ (col & 7);
                a[i] = *(s8v*)&As[row * 64 + slot * 8];
            }
#pragma unroll
            for (int j = 0; j < 4; ++j) {
                int row  = wn * 64 + j * 16 + col;
                int slot = (kk * 4 + quad) ^ (col & 7);
                b[j] = *(s8v*)&Bs[row * 64 + slot * 8];
            }
#pragma unroll
            for (int i = 0; i < 4; ++i)
#pragma unroll
                for (int j = 0; j < 4; ++j)
                    acc[i][j] = __builtin_amdgcn_mfma_f32_16x16x32_bf16(
                        a[i], b[j], acc[i][j], 0, 0, 0);
        }
    }

#pragma unroll
    for (int cc = 0; cc < 4; ++cc) {
        float s = c2part[cc];
        s += __shfl_xor(s, 1, 64);
        s += __shfl_xor(s, 2, 64);
        s += __shfl_xor(s, 4, 64);
        int row = (w * 4 + cc) * 8 + lrow;
        if (m0 == 0 && (lane & 7) == 0 && (n0 + row) < N)
            c2g[n0 + row] = s;
    }

    __syncthreads();
    __half* Cs = (__half*)smem;
#pragma unroll
    for (int i = 0; i < 4; ++i) {
#pragma unroll
        for (int j = 0; j < 4; ++j) {
#pragma unroll
            for (int v = 0; v < 4; ++v) {
                int ml = wm * 64 + i * 16 + quad * 4 + v;
                int nl = wn * 64 + j * 16 + col;
                int slot = ((nl >> 3) ^ (ml & 7));
                Cs[ml * 128 + slot * 8 + (nl & 7)] = __float2half(acc[i][j][v]);
            }
        }
    }
    __syncthreads();
#pragma unroll
    for (int it = 0; it < 8; ++it) {
        int idx = it * 256 + t;
        int row = idx >> 4;
        int o8  = idx & 15;
        int n   = n0 + o8 * 8;
        const __half* src = &Cs[row * 128 + ((o8 ^ (row & 7)) * 8)];
        __half* dst = Sm + (size_t)(m0 + row) * N + n;
        if (n + 7 < N) {
            *(uint4*)dst = *(const uint4*)src;
        } else if (n < N) {
            for (int e = 0; e < 8 && n + e < N; ++e) dst[e] = src[e];
        }
    }
}

// ------------------------------------------------- fused per-row (1024 thr):
// hist -> threshold -> collect -> exact f64 top-K -> class scatter -> log
// d2mode=1: Sm holds f16 d2 directly. d2mode=0: Sm holds S, d2 = fr+c2-2S.
__global__ __launch_bounds__(1024)
void fused_select(const __half* __restrict__ Sm, const float* __restrict__ f2,
                  const float* __restrict__ c2,
                  const float* __restrict__ F, const float* __restrict__ C,
                  const int* __restrict__ labels, const float* __restrict__ weight,
                  float* __restrict__ out, int N, int d2mode)
{
    __shared__ unsigned hist[NBINS * HREP]; // 16 KB, 4 replicated copies
    __shared__ float    fs[D_DIM];
    __shared__ int      idxs[CAND_MAX];
    __shared__ double   dists[CAND_MAX];
    __shared__ float    p[NCLS];
    __shared__ float    red[1024];
    __shared__ unsigned scanbuf[256];
    __shared__ float    sT;
    __shared__ unsigned scnt;

    const int r = blockIdx.x, t = threadIdx.x;
    for (int b = t; b < NBINS * HREP; b += 1024) hist[b] = 0u;
    for (int c = t; c < NCLS; c += 1024) p[c] = 0.f;
    for (int k = t; k < D_DIM; k += 1024) fs[k] = F[(size_t)r * D_DIM + k];
    if (t == 0) { sT = 1e30f; scnt = 0u; }
    __syncthreads();

    const float fr = f2[r];
    const __half* srow = Sm + (size_t)r * N;

    // ---- pass 1: histogram, 8 elems/thread/iter (N % 8 == 0)
    for (int j = t * 8; j < N; j += 8192) {
        uint4 sv = *(const uint4*)(srow + j);
        float2 s0 = __half22float2(*(__half2*)&sv.x);
        float2 s1 = __half22float2(*(__half2*)&sv.y);
        float2 s2 = __half22float2(*(__half2*)&sv.z);
        float2 s3 = __half22float2(*(__half2*)&sv.w);
        float d2v[8];
        if (d2mode) {
            d2v[0]=s0.x; d2v[1]=s0.y; d2v[2]=s1.x; d2v[3]=s1.y;
            d2v[4]=s2.x; d2v[5]=s2.y; d2v[6]=s3.x; d2v[7]=s3.y;
        } else {
            float4 ca = *(const float4*)(c2 + j);
            float4 cb = *(const float4*)(c2 + j + 4);
            d2v[0]=fr+ca.x-2.f*s0.x; d2v[1]=fr+ca.y-2.f*s0.y;
            d2v[2]=fr+ca.z-2.f*s1.x; d2v[3]=fr+ca.w-2.f*s1.y;
            d2v[4]=fr+cb.x-2.f*s2.x; d2v[5]=fr+cb.y-2.f*s2.y;
            d2v[6]=fr+cb.z-2.f*s3.x; d2v[7]=fr+cb.w-2.f*s3.y;
        }
#pragma unroll
        for (int e = 0; e < 8; ++e) {
            int b = (int)(d2v[e] * 0.5f);
            b = b < 0 ? 0 : (b > NBINS - 1 ? NBINS - 1 : b);
            atomicAdd(&hist[(b << 2) + (t & 3)], 1u);
        }
    }
    __syncthreads();

    // ---- threshold: blocked cumulative scan on first 256 threads
    if (t < 256) {
        unsigned loc[NBINS / 256];
        unsigned s = 0;
#pragma unroll
        for (int i = 0; i < NBINS / 256; ++i) {
            int bb = t * (NBINS / 256) + i;
            loc[i] = hist[(bb << 2) + 0] + hist[(bb << 2) + 1]
                   + hist[(bb << 2) + 2] + hist[(bb << 2) + 3];
            s += loc[i];
        }
        scanbuf[t] = s;
        __syncthreads();
        unsigned pre = 0;
        for (int u = 0; u < t; ++u) pre += scanbuf[u];
        if (pre < KSEL && pre + s >= KSEL) {
            unsigned cum = pre;
            int b = NBINS - 1;
#pragma unroll
            for (int i = 0; i < NBINS / 256; ++i) {
                cum += loc[i];
                if (cum >= KSEL) { b = t * (NBINS / 256) + i; break; }
            }
            sT = 2.0f * (float)(b + 1) + MARGIN;
        }
    } else {
        __syncthreads();
    }
    __syncthreads();
    const float Tr = sT;

    // ---- pass 2: collect candidate indices (row LLC-hot)
    for (int j = t * 8; j < N; j += 8192) {
        uint4 sv = *(const uint4*)(srow + j);
        float2 s0 = __half22float2(*(__half2*)&sv.x);
        float2 s1 = __half22float2(*(__half2*)&sv.y);
        float2 s2 = __half22float2(*(__half2*)&sv.z);
        float2 s3 = __half22float2(*(__half2*)&sv.w);
        float d2v[8];
        if (d2mode) {
            d2v[0]=s0.x; d2v[1]=s0.y; d2v[2]=s1.x; d2v[3]=s1.y;
            d2v[4]=s2.x; d2v[5]=s2.y; d2v[6]=s3.x; d2v[7]=s3.y;
        } else {
            float4 ca = *(const float4*)(c2 + j);
            float4 cb = *(const float4*)(c2 + j + 4);
            d2v[0]=fr+ca.x-2.f*s0.x; d2v[1]=fr+ca.y-2.f*s0.y;
            d2v[2]=fr+ca.z-2.f*s1.x; d2v[3]=fr+ca.w-2.f*s1.y;
            d2v[4]=fr+cb.x-2.f*s2.x; d2v[5]=fr+cb.y-2.f*s2.y;
            d2v[6]=fr+cb.z-2.f*s3.x; d2v[7]=fr+cb.w-2.f*s3.y;
        }
#pragma unroll
        for (int e = 0; e < 8; ++e) {
            if (d2v[e] <= Tr) {
                unsigned pos = atomicAdd(&scnt, 1u);
                if (pos < CAND_MAX) idxs[pos] = j + e;
            }
        }
    }
    __syncthreads();
    int Nc = (int)scnt;
    if (Nc > CAND_MAX) Nc = CAND_MAX;

    // ---- exact f64 distances: one WAVE per candidate, coalesced C gather
    {
        const int wv = t >> 6, lane = t & 63;
        for (int i = wv; i < Nc; i += 16) {
            int ci = idxs[i];
            const float* cp = C + (size_t)ci * D_DIM;
            float4 a  = *(const float4*)(cp + lane * 8);
            float4 b  = *(const float4*)(cp + lane * 8 + 4);
            float4 fa = *(const float4*)(fs + lane * 8);
            float4 fb = *(const float4*)(fs + lane * 8 + 4);
            double d0 = (double)fa.x - (double)a.x;
            double d1 = (double)fa.y - (double)a.y;
            double d2 = (double)fa.z - (double)a.z;
            double d3 = (double)fa.w - (double)a.w;
            double d4 = (double)fb.x - (double)b.x;
            double d5 = (double)fb.y - (double)b.y;
            double d6 = (double)fb.z - (double)b.z;
            double d7 = (double)fb.w - (double)b.w;
            double acc = d0*d0 + d1*d1 + d2*d2 + d3*d3
                       + d4*d4 + d5*d5 + d6*d6 + d7*d7;
#pragma unroll
            for (int off = 32; off > 0; off >>= 1)
                acc += __shfl_down(acc, off, 64);
            if (lane == 0) dists[i] = acc;
        }
    }
    __syncthreads();

    // ---- exact rank-based top-KSEL (tie-break: lower index, lax.top_k order)
    int ksel = KSEL < Nc ? KSEL : Nc;
    for (int i = t; i < Nc; i += 1024) {
        double di = dists[i];
        int    ii = idxs[i];
        int rank = 0;
        for (int j = 0; j < Nc; ++j) {
            double dj = dists[j];
            rank += (dj < di) || (dj == di && idxs[j] < ii);
        }
        if (rank < ksel) {
            double wgt = exp(-di * GCONST) * exp((double)weight[ii]);
            atomicAdd(&p[labels[ii]], (float)wgt);
        }
    }
    __syncthreads();

    // ---- p==0 -> 1e-10, normalize, log
    float s = 0.f;
    for (int c = t; c < NCLS; c += 1024) {
        float v = p[c];
        if (v == 0.f) v = 1e-10f;
        p[c] = v;
        s += v;
    }
    red[t] = s;
    __syncthreads();
    for (int o = 512; o > 0; o >>= 1) {
        if (t < o) red[t] += red[t + o];
        __syncthreads();
    }
    float total = red[0];
    for (int c = t; c < NCLS; c += 1024)
        out[(size_t)r * NCLS + c] = logf(p[c] / total);
}

// ------------------------------------------------- launch
extern "C" void kernel_launch(void* const* d_in, const int* in_sizes, int n_in,
                              void* d_out, int out_size, void* d_ws, size_t ws_size,
                              hipStream_t stream)
{
    const float* features = (const float*)d_in[0];
    const float* centres  = (const float*)d_in[1];
    const int*   labels   = (const int*)d_in[2];
    const float* weight   = (const float*)d_in[3];
    const int B = in_sizes[0] / D_DIM;   // 512
    const int N = in_sizes[2];           // 100000
    float* out = (float*)d_out;

    uint8_t* w = (uint8_t*)d_ws;
    size_t off = 0;
    auto alloc = [&](size_t bytes) -> uint8_t* {
        uint8_t* ptr = w + off;
        off = (off + bytes + 255) & ~(size_t)255;
        return ptr;
    };
    float*          f2 = (float*)alloc((size_t)B * 4);
    float*          c2 = (float*)alloc((size_t)N * 4);
    unsigned short* Fb = (unsigned short*)alloc((size_t)B * D_DIM * 2);
    __half*         Sm = (__half*)alloc((size_t)B * N * 2);

    const size_t need_cb = off + (size_t)N * D_DIM * 2;
    const bool   full    = ws_size >= need_cb;

    convertF<<<B, 256, 0, stream>>>(features, Fb, f2);

    if (full) {
        unsigned short* Cb = (unsigned short*)alloc((size_t)N * D_DIM * 2);
        convertC<<<4096, 256, 0, stream>>>(centres, Cb, c2, N);
        dim3 ggrid(B / 256, (N + 127) / 128);   // m fastest
        mfma_gemm_pure<<<ggrid, 512, 0, stream>>>(Fb, Cb, f2, c2, Sm, N);
    } else {
        dim3 ggrid(B / 128, (N + 127) / 128);
        mfma_gemm_fused<<<ggrid, 256, 0, stream>>>(Fb, centres, c2, Sm, N);
    }

    fused_select<<<B, 1024, 0, stream>>>(Sm, f2, c2, features, centres,
                                         labels, weight, out, N, full ? 1 : 0);
}

// Round 4
// 464.225 us; speedup vs baseline: 1.0857x; 1.0857x over previous
//
#include <hip/hip_runtime.h>
#include <hip/hip_fp16.h>
#include <math.h>
#include <stdint.h>

#define D_DIM    512
#define NCLS     1000
#define KSEL     200
#define NBINS    1024         // bin width 2.0, covers d2 in [0, 2048)
#define HREP     4            // replicated LDS histograms (atomic contention)
#define CAND_MAX 2048
#define GCONST   0.005        // 1/(2*sigma^2), sigma=10
#define MARGIN   4.0f         // covers f16-d2 ulp (0.5) + bf16 GEMM error + bin edge

typedef short s8v __attribute__((ext_vector_type(8)));
typedef float f4v __attribute__((ext_vector_type(4)));

#define GLOAD_LDS16(gp, lp) __builtin_amdgcn_global_load_lds( \
    (const __attribute__((address_space(1))) void*)(gp),      \
    (__attribute__((address_space(3))) void*)(lp), 16, 0, 0)

// RTNE f32 -> bf16 (inputs finite)
static __device__ __forceinline__ unsigned short f2bf(float x) {
    unsigned u = __float_as_uint(x);
    return (unsigned short)((u + 0x7FFFu + ((u >> 16) & 1u)) >> 16);
}

// packed RTNE f32x2 -> bf16x2, single instruction (no builtin on gfx950)
static __device__ __forceinline__ unsigned cvt_pk_bf16(float lo, float hi) {
    unsigned r;
    asm("v_cvt_pk_bf16_f32 %0, %1, %2" : "=v"(r) : "v"(lo), "v"(hi));
    return r;
}

// ------------------------------------------------- convert F (+ row norms)
__global__ __launch_bounds__(256)
void convertF(const float* __restrict__ F, unsigned short* __restrict__ Fb,
              float* __restrict__ f2)
{
    __shared__ float red[256];
    const int r = blockIdx.x, t = threadIdx.x;
    float2 v = *(const float2*)(F + (size_t)r * D_DIM + t * 2);
    ushort2 o; o.x = f2bf(v.x); o.y = f2bf(v.y);
    *(ushort2*)(Fb + (size_t)r * D_DIM + t * 2) = o;
    red[t] = v.x * v.x + v.y * v.y;
    __syncthreads();
    for (int off = 128; off > 0; off >>= 1) {
        if (t < off) red[t] += red[t + off];
        __syncthreads();
    }
    if (t == 0) f2[r] = red[0];
}

// ------------------------------------------------- FUSED MFMA GEMM, BM=256
// 512 threads = 8 waves (4m x 2n), per-wave 64x64 output (4x4 16x16 frags).
// A staged via global_load_lds w=16 from bf16 Fb (octet-XOR swizzle applied
// on the per-lane GLOBAL source; LDS dest linear). B read as f32 from C,
// converted bf16 in-register (v_cvt_pk_bf16_f32), staged to LDS with the
// matching octet swizzle; c2 row norms accumulated on the fly. Next-K B f32
// prefetched during MFMA. Grid m-fastest: the 2 m-blocks of an n-stripe
// co-run, so C f32 is HBM-fetched ~once (second block LLC-hits — r3 FETCH
// evidence). Epilogue computes d2 = f2[m] + c2[n] - 2*S and stores f16 d2.
__global__ __launch_bounds__(512)
void mfma_gemm(const unsigned short* __restrict__ Fb,
               const float* __restrict__ C,
               const float* __restrict__ f2,
               __half* __restrict__ Dm, int N)
{
    __shared__ short smem[32 * 512 + 16 * 512];  // As 32 KB | Bs 16 KB
    __shared__ float c2s[128];
    short* As = smem;
    short* Bs = smem + 32 * 512;
    const int t    = threadIdx.x;
    const int lane = t & 63;
    const int w    = t >> 6;             // wave 0..7
    const int wm   = w >> 1, wn = w & 1; // wm 0..3 (64 rows), wn 0..1 (64 cols)
    const int m0   = blockIdx.x * 256;   // m fastest
    const int n0   = blockIdx.y * 128;
    const int lrow = lane >> 3;          // 0..7 within staging chunk
    const int oct  = (lane & 7) ^ lrow;  // swizzled global k octet
    const int quad = lane >> 4;          // 0..3
    const int col  = lane & 15;

    f4v acc[4][4];
#pragma unroll
    for (int i = 0; i < 4; ++i)
#pragma unroll
        for (int j = 0; j < 4; ++j) acc[i][j] = (f4v){0.f, 0.f, 0.f, 0.f};

    float  c2part[2] = {0.f, 0.f};
    float4 ra[2], rb[2];

    // preload B f32 for k0 = 0 (2 chunks/wave: 16 chunks = 128 rows)
#pragma unroll
    for (int cc = 0; cc < 2; ++cc) {
        int row = (w * 2 + cc) * 8 + lrow;
        int rg  = n0 + row; rg = rg < N ? rg : N - 1;   // clamp tail
        const float* gp = C + (size_t)rg * D_DIM + oct * 8;
        ra[cc] = *(const float4*)gp;
        rb[cc] = *(const float4*)(gp + 4);
    }

    for (int k0 = 0; k0 < D_DIM; k0 += 64) {
        __syncthreads();             // prev iter's MFMA done with LDS
#pragma unroll
        for (int cc = 0; cc < 4; ++cc) {
            int ch = w * 4 + cc;     // A chunks 0..31 (8 rows each, 256 rows)
            GLOAD_LDS16(Fb + (size_t)(m0 + ch * 8 + lrow) * D_DIM + k0 + oct * 8,
                        &As[ch * 512]);
        }
#pragma unroll
        for (int cc = 0; cc < 2; ++cc) {
            int row = (w * 2 + cc) * 8 + lrow;
            float4 va = ra[cc], vb = rb[cc];
            c2part[cc] += va.x*va.x + va.y*va.y + va.z*va.z + va.w*va.w
                        + vb.x*vb.x + vb.y*vb.y + vb.z*vb.z + vb.w*vb.w;
            uint4 o;
            o.x = cvt_pk_bf16(va.x, va.y);
            o.y = cvt_pk_bf16(va.z, va.w);
            o.z = cvt_pk_bf16(vb.x, vb.y);
            o.w = cvt_pk_bf16(vb.z, vb.w);
            // LDS slot (lane&7) holds global octet (lane&7)^lrow == oct ✓
            *(uint4*)&Bs[row * 64 + (lane & 7) * 8] = o;
        }
        __syncthreads();             // As arrived (vmcnt drain) + Bs visible

        if (k0 + 64 < D_DIM) {       // prefetch next B f32 during MFMA
#pragma unroll
            for (int cc = 0; cc < 2; ++cc) {
                int row = (w * 2 + cc) * 8 + lrow;
                int rg  = n0 + row; rg = rg < N ? rg : N - 1;
                const float* gp = C + (size_t)rg * D_DIM + (k0 + 64) + oct * 8;
                ra[cc] = *(const float4*)gp;
                rb[cc] = *(const float4*)(gp + 4);
            }
        }

#pragma unroll
        for (int kk = 0; kk < 2; ++kk) {
            int slot = (kk * 4 + quad) ^ (col & 7);
            s8v b[4];
#pragma unroll
            for (int j = 0; j < 4; ++j) {
                int row = wn * 64 + j * 16 + col;
                b[j] = *(s8v*)&Bs[row * 64 + slot * 8];
            }
#pragma unroll
            for (int i = 0; i < 4; ++i) {
                int row = wm * 64 + i * 16 + col;
                s8v a = *(s8v*)&As[row * 64 + slot * 8];
#pragma unroll
                for (int j = 0; j < 4; ++j)
                    acc[i][j] = __builtin_amdgcn_mfma_f32_16x16x32_bf16(
                        a, b[j], acc[i][j], 0, 0, 0);
            }
        }
    }

    // ---- c2 row norms -> LDS (reduce over the 8 lanes sharing each row)
#pragma unroll
    for (int cc = 0; cc < 2; ++cc) {
        float s = c2part[cc];
        s += __shfl_xor(s, 1, 64);
        s += __shfl_xor(s, 2, 64);
        s += __shfl_xor(s, 4, 64);
        int row = (w * 2 + cc) * 8 + lrow;
        if ((lane & 7) == 0) c2s[row] = s;
    }
    __syncthreads();                 // c2s visible; MFMA LDS reads done

    // ---- epilogue: d2 = f2[m] + c2[n] - 2*S, pack f16 (octet-swizzled), store
    float c2v[4];
#pragma unroll
    for (int j = 0; j < 4; ++j)
        c2v[j] = c2s[wn * 64 + j * 16 + col];
    float fv[4][4];
#pragma unroll
    for (int i = 0; i < 4; ++i)
#pragma unroll
        for (int v = 0; v < 4; ++v)
            fv[i][v] = f2[m0 + wm * 64 + i * 16 + quad * 4 + v];

    __half* Cs = (__half*)smem;      // 128 x 128 f16 = 32 KB (half tile)
#pragma unroll
    for (int h = 0; h < 2; ++h) {
        __syncthreads();             // smem free (h=0) / prev half stored (h=1)
        if ((wm >> 1) == h) {
            int mlb = (wm & 1) * 64;
#pragma unroll
            for (int i = 0; i < 4; ++i) {
#pragma unroll
                for (int j = 0; j < 4; ++j) {
#pragma unroll
                    for (int v = 0; v < 4; ++v) {
                        int ml = mlb + i * 16 + quad * 4 + v;   // 0..127
                        int nl = wn * 64 + j * 16 + col;        // 0..127
                        float d2 = fv[i][v] + c2v[j] - 2.f * acc[i][j][v];
                        int slot = (nl >> 3) ^ (ml & 7);
                        Cs[ml * 128 + slot * 8 + (nl & 7)] = __float2half(d2);
                    }
                }
            }
        }
        __syncthreads();
#pragma unroll
        for (int it = 0; it < 4; ++it) {
            int idx = it * 512 + t;  // 0..2047
            int row = idx >> 4;      // 0..127
            int o8  = idx & 15;
            int n   = n0 + o8 * 8;
            const __half* src = &Cs[row * 128 + ((o8 ^ (row & 7)) * 8)];
            __half* dst = Dm + (size_t)(m0 + h * 128 + row) * N + n;
            if (n + 7 < N) {
                *(uint4*)dst = *(const uint4*)src;
            } else if (n < N) {
                for (int e = 0; e < 8 && n + e < N; ++e) dst[e] = src[e];
            }
        }
    }
}

// ------------------------------------------------- fused per-row (1024 thr):
// Dm holds f16 d2 directly. hist -> threshold -> collect -> exact f64 top-K
// -> class scatter -> log.
__global__ __launch_bounds__(1024)
void fused_select(const __half* __restrict__ Dm,
                  const float* __restrict__ F, const float* __restrict__ C,
                  const int* __restrict__ labels, const float* __restrict__ weight,
                  float* __restrict__ out, int N)
{
    __shared__ unsigned hist[NBINS * HREP]; // 16 KB, 4 replicated copies
    __shared__ float    fs[D_DIM];
    __shared__ int      idxs[CAND_MAX];
    __shared__ double   dists[CAND_MAX];
    __shared__ float    p[NCLS];
    __shared__ float    red[1024];
    __shared__ unsigned scanbuf[256];
    __shared__ float    sT;
    __shared__ unsigned scnt;

    const int r = blockIdx.x, t = threadIdx.x;
    for (int b = t; b < NBINS * HREP; b += 1024) hist[b] = 0u;
    for (int c = t; c < NCLS; c += 1024) p[c] = 0.f;
    for (int k = t; k < D_DIM; k += 1024) fs[k] = F[(size_t)r * D_DIM + k];
    if (t == 0) { sT = 1e30f; scnt = 0u; }
    __syncthreads();

    const __half* srow = Dm + (size_t)r * N;

    // ---- pass 1: histogram, 8 elems/thread/iter (N % 8 == 0)
    for (int j = t * 8; j < N; j += 8192) {
        uint4 sv = *(const uint4*)(srow + j);
        float2 s0 = __half22float2(*(__half2*)&sv.x);
        float2 s1 = __half22float2(*(__half2*)&sv.y);
        float2 s2 = __half22float2(*(__half2*)&sv.z);
        float2 s3 = __half22float2(*(__half2*)&sv.w);
        float d2v[8] = { s0.x, s0.y, s1.x, s1.y, s2.x, s2.y, s3.x, s3.y };
#pragma unroll
        for (int e = 0; e < 8; ++e) {
            int b = (int)(d2v[e] * 0.5f);
            b = b < 0 ? 0 : (b > NBINS - 1 ? NBINS - 1 : b);
            atomicAdd(&hist[(b << 2) + (t & 3)], 1u);
        }
    }
    __syncthreads();

    // ---- threshold: blocked cumulative scan on first 256 threads
    if (t < 256) {
        unsigned loc[NBINS / 256];
        unsigned s = 0;
#pragma unroll
        for (int i = 0; i < NBINS / 256; ++i) {
            int bb = t * (NBINS / 256) + i;
            loc[i] = hist[(bb << 2) + 0] + hist[(bb << 2) + 1]
                   + hist[(bb << 2) + 2] + hist[(bb << 2) + 3];
            s += loc[i];
        }
        scanbuf[t] = s;
        __syncthreads();
        unsigned pre = 0;
        for (int u = 0; u < t; ++u) pre += scanbuf[u];
        if (pre < KSEL && pre + s >= KSEL) {
            unsigned cum = pre;
            int b = NBINS - 1;
#pragma unroll
            for (int i = 0; i < NBINS / 256; ++i) {
                cum += loc[i];
                if (cum >= KSEL) { b = t * (NBINS / 256) + i; break; }
            }
            sT = 2.0f * (float)(b + 1) + MARGIN;
        }
    } else {
        __syncthreads();
    }
    __syncthreads();
    const float Tr = sT;

    // ---- pass 2: collect candidate indices (row LLC-hot)
    for (int j = t * 8; j < N; j += 8192) {
        uint4 sv = *(const uint4*)(srow + j);
        float2 s0 = __half22float2(*(__half2*)&sv.x);
        float2 s1 = __half22float2(*(__half2*)&sv.y);
        float2 s2 = __half22float2(*(__half2*)&sv.z);
        float2 s3 = __half22float2(*(__half2*)&sv.w);
        float d2v[8] = { s0.x, s0.y, s1.x, s1.y, s2.x, s2.y, s3.x, s3.y };
#pragma unroll
        for (int e = 0; e < 8; ++e) {
            if (d2v[e] <= Tr) {
                unsigned pos = atomicAdd(&scnt, 1u);
                if (pos < CAND_MAX) idxs[pos] = j + e;
            }
        }
    }
    __syncthreads();
    int Nc = (int)scnt;
    if (Nc > CAND_MAX) Nc = CAND_MAX;

    // ---- exact f64 distances: one WAVE per candidate, coalesced C gather
    {
        const int wv = t >> 6, lane = t & 63;
        for (int i = wv; i < Nc; i += 16) {
            int ci = idxs[i];
            const float* cp = C + (size_t)ci * D_DIM;
            float4 a  = *(const float4*)(cp + lane * 8);
            float4 b  = *(const float4*)(cp + lane * 8 + 4);
            float4 fa = *(const float4*)(fs + lane * 8);
            float4 fb = *(const float4*)(fs + lane * 8 + 4);
            double d0 = (double)fa.x - (double)a.x;
            double d1 = (double)fa.y - (double)a.y;
            double d2 = (double)fa.z - (double)a.z;
            double d3 = (double)fa.w - (double)a.w;
            double d4 = (double)fb.x - (double)b.x;
            double d5 = (double)fb.y - (double)b.y;
            double d6 = (double)fb.z - (double)b.z;
            double d7 = (double)fb.w - (double)b.w;
            double acc = d0*d0 + d1*d1 + d2*d2 + d3*d3
                       + d4*d4 + d5*d5 + d6*d6 + d7*d7;
#pragma unroll
            for (int off = 32; off > 0; off >>= 1)
                acc += __shfl_down(acc, off, 64);
            if (lane == 0) dists[i] = acc;
        }
    }
    __syncthreads();

    // ---- exact rank-based top-KSEL (tie-break: lower index, lax.top_k order)
    int ksel = KSEL < Nc ? KSEL : Nc;
    for (int i = t; i < Nc; i += 1024) {
        double di = dists[i];
        int    ii = idxs[i];
        int rank = 0;
        for (int j = 0; j < Nc; ++j) {
            double dj = dists[j];
            rank += (dj < di) || (dj == di && idxs[j] < ii);
        }
        if (rank < ksel) {
            double wgt = exp(-di * GCONST) * exp((double)weight[ii]);
            atomicAdd(&p[labels[ii]], (float)wgt);
        }
    }
    __syncthreads();

    // ---- p==0 -> 1e-10, normalize, log
    float s = 0.f;
    for (int c = t; c < NCLS; c += 1024) {
        float v = p[c];
        if (v == 0.f) v = 1e-10f;
        p[c] = v;
        s += v;
    }
    red[t] = s;
    __syncthreads();
    for (int o = 512; o > 0; o >>= 1) {
        if (t < o) red[t] += red[t + o];
        __syncthreads();
    }
    float total = red[0];
    for (int c = t; c < NCLS; c += 1024)
        out[(size_t)r * NCLS + c] = logf(p[c] / total);
}

// ------------------------------------------------- launch
extern "C" void kernel_launch(void* const* d_in, const int* in_sizes, int n_in,
                              void* d_out, int out_size, void* d_ws, size_t ws_size,
                              hipStream_t stream)
{
    const float* features = (const float*)d_in[0];
    const float* centres  = (const float*)d_in[1];
    const int*   labels   = (const int*)d_in[2];
    const float* weight   = (const float*)d_in[3];
    const int B = in_sizes[0] / D_DIM;   // 512
    const int N = in_sizes[2];           // 100000
    float* out = (float*)d_out;

    uint8_t* w = (uint8_t*)d_ws;
    size_t off = 0;
    auto alloc = [&](size_t bytes) -> uint8_t* {
        uint8_t* ptr = w + off;
        off = (off + bytes + 255) & ~(size_t)255;
        return ptr;
    };
    float*          f2 = (float*)alloc((size_t)B * 4);
    unsigned short* Fb = (unsigned short*)alloc((size_t)B * D_DIM * 2);
    __half*         Dm = (__half*)alloc((size_t)B * N * 2);
    (void)ws_size;

    convertF<<<B, 256, 0, stream>>>(features, Fb, f2);

    dim3 ggrid(B / 256, (N + 127) / 128);   // m fastest
    mfma_gemm<<<ggrid, 512, 0, stream>>>(Fb, centres, f2, Dm, N);

    fused_select<<<B, 1024, 0, stream>>>(Dm, features, centres,
                                         labels, weight, out, N);
}